// Round 4
// baseline (244.745 us; speedup 1.0000x reference)
//
#include <hip/hip_runtime.h>

#define HWD 56
#define NWIN 7
#define P2 49
#define CIN 128
#define COUT 384
#define NB 8
#define SCALE 0.08838834764831843f

typedef __attribute__((ext_vector_type(8))) short bf16x8;
typedef __attribute__((ext_vector_type(4))) float f32x4;
typedef __attribute__((ext_vector_type(8))) unsigned short u16x8;
typedef unsigned short ushort_t;

__device__ inline unsigned short f2bf(float f) {
  unsigned int u = __float_as_uint(f);
  unsigned int r = (u + 0x7fffu + ((u >> 16) & 1u)) >> 16;
  return (unsigned short)r;
}
__device__ inline float bf2f(unsigned short b) {
  return __uint_as_float(((unsigned int)b) << 16);
}

// ---------------- window mean of x + fp32 projection (routing path) + bf16 x emit ----------------
// grid (49, 8, 2), block 256
__global__ __launch_bounds__(256) void meanproj_kernel(
    const float* __restrict__ xin, const float* __restrict__ yin,
    const float* __restrict__ Wx, const float* __restrict__ Bx,
    const float* __restrict__ Wy, const float* __restrict__ By,
    ushort_t* __restrict__ xbfx, ushort_t* __restrict__ xbfy,
    float* __restrict__ qwx, float* __restrict__ kwx,
    float* __restrict__ qwy, float* __restrict__ kwy)
{
  const int p = blockIdx.x, n = blockIdx.y, br = blockIdx.z;
  const float* X  = br ? yin : xin;
  const float* W  = br ? Wy  : Wx;
  const float* Bv = br ? By  : Bx;
  ushort_t* xb = (br ? xbfy : xbfx) + (size_t)(n * P2 + p) * 64 * CIN;
  float* qw = br ? qwy : qwx;
  float* kw = br ? kwy : kwx;

  __shared__ float sm[2][128];
  __shared__ float mxs[128];
  const int t = threadIdx.x;
  const int wr = p / NWIN, wc = p % NWIN;
  const int ch = t & 127, half = t >> 7;

  float s = 0.f;
#pragma unroll 4
  for (int i = 0; i < 32; ++i) {
    int pix = half * 32 + i;
    int a = wr * 8 + (pix >> 3), b = wc * 8 + (pix & 7);
    float v = X[(((size_t)n * HWD + a) * HWD + b) * CIN + ch];
    s += v;
    xb[pix * CIN + ch] = f2bf(v);
  }
  sm[half][ch] = s;
  __syncthreads();
  if (t < 128) mxs[t] = (sm[0][t] + sm[1][t]) * (1.f / 64.f);
  __syncthreads();

  // fp32 exact projection for routing ordering
  float acc = Bv[t];
#pragma unroll 8
  for (int k = 0; k < 128; ++k) acc = fmaf(mxs[k], W[(size_t)k * COUT + t], acc);
  if (t < 128) qw[(n * P2 + p) * 128 + t] = acc;
  else         kw[(n * P2 + p) * 128 + (t - 128)] = acc;
}

// ---------------- W transpose -> bf16 Wt[cout][k] ----------------
// grid (3, 2), block 128
__global__ __launch_bounds__(128) void wt_kernel(
    const float* __restrict__ Wx, const float* __restrict__ Wy,
    ushort_t* __restrict__ Wtx, ushort_t* __restrict__ Wty)
{
  const int br = blockIdx.y;
  const float* W = br ? Wy : Wx;
  ushort_t* Wt = br ? Wty : Wtx;
  const int c = blockIdx.x * 128 + threadIdx.x;
  for (int k8 = 0; k8 < 128; k8 += 8) {
    u16x8 buf;
#pragma unroll
    for (int i = 0; i < 8; ++i) buf[i] = f2bf(W[(size_t)(k8 + i) * COUT + c]);
    *(u16x8*)&Wt[(size_t)c * 128 + k8] = buf;
  }
}

// ---------------- routing: top-4 window indices (fp32) ----------------
__global__ __launch_bounds__(256) void route_kernel(
    const float* __restrict__ qwx, const float* __restrict__ kwx,
    const float* __restrict__ qwy, const float* __restrict__ kwy,
    int* __restrict__ idxx, int* __restrict__ idxy)
{
  const int br = blockIdx.x, n = blockIdx.y;
  const float* qw = br ? qwy : qwx;
  const float* kw = br ? kwy : kwx;
  int* idx = br ? idxy : idxx;

  __shared__ float qs[P2][128];
  __shared__ float ks[P2][128];
  __shared__ float ls[P2][52];
  const int t = threadIdx.x;
  for (int e = t; e < P2 * 128; e += 256) {
    qs[e >> 7][e & 127] = qw[(size_t)n * P2 * 128 + e];
    ks[e >> 7][e & 127] = kw[(size_t)n * P2 * 128 + e];
  }
  __syncthreads();
  for (int pair = t; pair < P2 * P2; pair += 256) {
    int r = pair / P2, j = pair % P2;
    float d = 0.f;
#pragma unroll
    for (int c4 = 0; c4 < 32; ++c4) {
      float4 a = *(const float4*)&qs[r][c4 * 4];
      float4 b = *(const float4*)&ks[j][c4 * 4];
      d = fmaf(a.x, b.x, d); d = fmaf(a.y, b.y, d);
      d = fmaf(a.z, b.z, d); d = fmaf(a.w, b.w, d);
    }
    ls[r][j] = d;
  }
  __syncthreads();
  if (t < P2) {
    int ch[4];
    for (int s = 0; s < 4; ++s) {
      float best = -1e30f; int bi = 0;
      for (int j = 0; j < P2; ++j) {
        bool taken = false;
        for (int u = 0; u < s; ++u) taken = taken || (ch[u] == j);
        if (!taken && ls[t][j] > best) { best = ls[t][j]; bi = j; }
      }
      ch[s] = bi;
      idx[((size_t)n * P2 + t) * 4 + s] = bi;
    }
  }
}

// ---------------- qkv GEMM: out[gw][pix][ch] bf16; q couts pre-scaled by SCALE ----------------
// grid (196, 3, 2); block 256 = 4 waves
#define AS 136
__global__ __launch_bounds__(256) void qkv_gemm_kernel(
    const ushort_t* __restrict__ xbfx, const ushort_t* __restrict__ xbfy,
    const ushort_t* __restrict__ Wtx, const ushort_t* __restrict__ Wty,
    const float* __restrict__ Bx, const float* __restrict__ By,
    ushort_t* __restrict__ qkvx, ushort_t* __restrict__ qkvy)
{
  const int mt = blockIdx.x, nt = blockIdx.y, br = blockIdx.z;
  const ushort_t* Xb = br ? xbfy : xbfx;
  const ushort_t* Wt = br ? Wty : Wtx;
  const float* Bv = br ? By : Bx;
  ushort_t* out = br ? qkvy : qkvx;

  __shared__ ushort_t a_s[128 * AS];  // [token][k]
  __shared__ ushort_t b_s[128 * AS];  // [cout][k]

  const int t = threadIdx.x;
#pragma unroll
  for (int it = 0; it < 8; ++it) {
    int row = it * 16 + (t >> 4);
    int e8 = (t & 15) * 8;
    *(u16x8*)&a_s[row * AS + e8] = *(const u16x8*)&Xb[((size_t)mt * 128 + row) * 128 + e8];
    *(u16x8*)&b_s[row * AS + e8] = *(const u16x8*)&Wt[((size_t)nt * 128 + row) * 128 + e8];
  }
  __syncthreads();

  const int wv = t >> 6, wm = wv >> 1, wn = wv & 1;
  const int lane = t & 63, qd = lane >> 4, m16 = lane & 15;

  f32x4 acc[4][4];
#pragma unroll
  for (int i = 0; i < 4; ++i)
#pragma unroll
    for (int j = 0; j < 4; ++j) acc[i][j] = (f32x4){0.f, 0.f, 0.f, 0.f};

#pragma unroll
  for (int ks = 0; ks < 4; ++ks) {
    bf16x8 af[4], bfr[4];
#pragma unroll
    for (int fi = 0; fi < 4; ++fi)
      af[fi] = *(const bf16x8*)&a_s[(wm * 64 + fi * 16 + m16) * AS + ks * 32 + qd * 8];
#pragma unroll
    for (int fj = 0; fj < 4; ++fj)
      bfr[fj] = *(const bf16x8*)&b_s[(wn * 64 + fj * 16 + m16) * AS + ks * 32 + qd * 8];
    // D = W_tile x X_tile^T : m=cout (reg), n=token (lane) -> [pix][ch] vector stores
#pragma unroll
    for (int fi = 0; fi < 4; ++fi)
#pragma unroll
      for (int fj = 0; fj < 4; ++fj)
        acc[fi][fj] = __builtin_amdgcn_mfma_f32_16x16x32_bf16(bfr[fj], af[fi], acc[fi][fj], 0, 0, 0);
  }

  const float scl = (nt == 0) ? SCALE : 1.0f;  // q channels pre-scaled
#pragma unroll
  for (int fj = 0; fj < 4; ++fj) {
    int chb = nt * 128 + wn * 64 + fj * 16 + qd * 4;
    float4 b4 = *(const float4*)&Bv[chb];
#pragma unroll
    for (int fi = 0; fi < 4; ++fi) {
      int tok = wm * 64 + fi * 16 + m16;
      ushort4 st = {f2bf((acc[fi][fj][0] + b4.x) * scl), f2bf((acc[fi][fj][1] + b4.y) * scl),
                    f2bf((acc[fi][fj][2] + b4.z) * scl), f2bf((acc[fi][fj][3] + b4.w) * scl)};
      *(ushort4*)&out[((size_t)mt * 128 + tok) * COUT + chb] = st;
    }
  }
}

// ---------------- fused gather + MFMA attention + LDS-halo LEPE ----------------
// grid (49, 8, 16): z = head*2 + dir; block 256 = 4 waves, wave wv owns q-rows [16wv,16wv+16)
#define KR 24
__global__ __launch_bounds__(256) void attn_kernel(
    const ushort_t* __restrict__ qkvx, const ushort_t* __restrict__ qkvy,
    const int* __restrict__ idxx, const int* __restrict__ idxy,
    const float* __restrict__ wlx, const float* __restrict__ blx,
    const float* __restrict__ wly, const float* __restrict__ bly,
    float* __restrict__ dout)
{
  const int p = blockIdx.x, n = blockIdx.y, z = blockIdx.z;
  const int h = z >> 1, dir = z & 1;
  const ushort_t* qkvQ = dir ? qkvy : qkvx;
  const ushort_t* qkvV = dir ? qkvx : qkvy;
  const int* idxK = dir ? idxy : idxx;
  const int* idxV = dir ? idxx : idxy;
  const float* wl = dir ? wlx : wly;   // dir0 writes out_y -> lepe_y
  const float* bl = dir ? blx : bly;
  const size_t OUTHALF = (size_t)NB * HWD * HWD * CIN;
  float* outp = dout + (dir ? 0 : OUTHALF);

  __shared__ ushort_t kb[256 * KR];   // [key][16ch], stride 24 (2-way free)
  __shared__ ushort_t qb[64 * KR];
  __shared__ ushort_t vt[16 * 264];   // [ch][key]
  __shared__ float halo[100 * 20];    // [10x10 pix][16ch fp32], stride 20
  __shared__ float wls[160];          // [tap 0..8][16ch] + [bias][16ch]

  const int t = threadIdx.x;
  const int wv = t >> 6, r = t & 63;
  const int wr = p / NWIN, wc = p % NWIN;

  const int kwin = idxK[((size_t)n * P2 + p) * 4 + wv];
  const int vwin = idxV[((size_t)n * P2 + p) * 4 + wv];

  // K: key t <- window kwin pixel (t&63); [pix][ch] layout = direct 2x16B copy
  {
    const ushort_t* src = qkvQ + ((size_t)(n * P2 + kwin) * 64 + r) * COUT + 128 + h * 16;
    *(u16x8*)&kb[t * KR] = *(const u16x8*)src;
    *(u16x8*)&kb[t * KR + 8] = *(const u16x8*)(src + 8);
  }
  // Q: direct copy (already scaled by SCALE in gemm)
  if (t < 64) {
    const ushort_t* src = qkvQ + ((size_t)(n * P2 + p) * 64 + t) * COUT + h * 16;
    *(u16x8*)&qb[t * KR] = *(const u16x8*)src;
    *(u16x8*)&qb[t * KR + 8] = *(const u16x8*)(src + 8);
  }
  // V transposed: lane r = pixel of window vwin -> vt[ch][wv*64+r]
  {
    const ushort_t* src = qkvV + ((size_t)(n * P2 + vwin) * 64 + r) * COUT + 256 + h * 16;
    u16x8 v0 = *(const u16x8*)src;
    u16x8 v1 = *(const u16x8*)(src + 8);
#pragma unroll
    for (int c = 0; c < 8; ++c) {
      vt[c * 264 + wv * 64 + r] = v0[c];
      vt[(c + 8) * 264 + wv * 64 + r] = v1[c];
    }
  }
  // LEPE halo: 10x10 pixels x 16ch fp32 (zero outside image)
  if (t < 200) {
    int hp = t >> 1, hf = t & 1;
    int A = wr * 8 - 1 + (int)((unsigned)hp / 10u);
    int B = wc * 8 - 1 + (int)((unsigned)hp % 10u);
    f32x4 f0 = {0.f, 0.f, 0.f, 0.f}, f1 = {0.f, 0.f, 0.f, 0.f};
    if ((unsigned)A < (unsigned)HWD && (unsigned)B < (unsigned)HWD) {
      int gw = (A >> 3) * NWIN + (B >> 3);
      int pix = (A & 7) * 8 + (B & 7);
      u16x8 vv = *(const u16x8*)(qkvV + ((size_t)(n * P2 + gw) * 64 + pix) * COUT + 256 + h * 16 + hf * 8);
      f0[0] = bf2f(vv[0]); f0[1] = bf2f(vv[1]); f0[2] = bf2f(vv[2]); f0[3] = bf2f(vv[3]);
      f1[0] = bf2f(vv[4]); f1[1] = bf2f(vv[5]); f1[2] = bf2f(vv[6]); f1[3] = bf2f(vv[7]);
    }
    *(f32x4*)&halo[hp * 20 + hf * 8] = f0;
    *(f32x4*)&halo[hp * 20 + hf * 8 + 4] = f1;
  }
  // LEPE weights + bias
  if (t < 160) {
    int row = t >> 4, c = t & 15;
    wls[t] = (row < 9) ? wl[(h * 16 + c) * 9 + row] : bl[h * 16 + c];
  }
  __syncthreads();

  const int qd = r >> 4, m16 = r & 15;
  const f32x4 zf = {0.f, 0.f, 0.f, 0.f};

  bf16x8 qf = (bf16x8)(short)0;
  if (qd < 2) qf = *(const bf16x8*)&qb[(wv * 16 + m16) * KR + qd * 8];

  // Phase 1: all scores S^T (lane: qrow=m16, keys c*32+qd*4+rr / +16)
  f32x4 s[8][2];
#pragma unroll
  for (int c = 0; c < 8; ++c) {
    bf16x8 kf0 = (bf16x8)(short)0, kf1 = (bf16x8)(short)0;
    if (qd < 2) {
      kf0 = *(const bf16x8*)&kb[(c * 32 + m16) * KR + qd * 8];
      kf1 = *(const bf16x8*)&kb[(c * 32 + 16 + m16) * KR + qd * 8];
    }
    s[c][0] = __builtin_amdgcn_mfma_f32_16x16x32_bf16(kf0, qf, zf, 0, 0, 0);
    s[c][1] = __builtin_amdgcn_mfma_f32_16x16x32_bf16(kf1, qf, zf, 0, 0, 0);
  }

  // Phase 2: single-pass softmax over all 256 keys (scale folded into Q)
  float m = -1e30f;
#pragma unroll
  for (int c = 0; c < 8; ++c)
#pragma unroll
    for (int hh = 0; hh < 2; ++hh)
#pragma unroll
      for (int rr = 0; rr < 4; ++rr) m = fmaxf(m, s[c][hh][rr]);
  m = fmaxf(m, __shfl_xor(m, 16));
  m = fmaxf(m, __shfl_xor(m, 32));
  float l = 0.f;
#pragma unroll
  for (int c = 0; c < 8; ++c)
#pragma unroll
    for (int hh = 0; hh < 2; ++hh)
#pragma unroll
      for (int rr = 0; rr < 4; ++rr) {
        float e = __expf(s[c][hh][rr] - m);
        s[c][hh][rr] = e;
        l += e;
      }
  l += __shfl_xor(l, 16);
  l += __shfl_xor(l, 32);
  const float inv = 1.f / l;

  // Phase 3: O^T = V^T * P^T
  f32x4 oacc = {0.f, 0.f, 0.f, 0.f};
#pragma unroll
  for (int c = 0; c < 8; ++c) {
    int pk[4];
#pragma unroll
    for (int rr = 0; rr < 4; ++rr)
      pk[rr] = (int)((unsigned int)f2bf(s[c][0][rr]) | ((unsigned int)f2bf(s[c][1][rr]) << 16));
    u16x8 pfu;
#pragma unroll
    for (int j = 0; j < 8; ++j) {
      int srcl = (((qd & 1) * 2 + (j >> 2)) << 4) + m16;
      int w = __shfl(pk[j & 3], srcl);
      pfu[j] = (qd < 2) ? (unsigned short)(w & 0xffff) : (unsigned short)((unsigned)w >> 16);
    }
    bf16x8 vtf = *(const bf16x8*)&vt[m16 * 264 + c * 32 + qd * 8];
    oacc = __builtin_amdgcn_mfma_f32_16x16x32_bf16(vtf, *(bf16x8*)&pfu, oacc, 0, 0, 0);
  }

  // Epilogue: lane = O^T[ch=h*16+qd*4+rr][qrow=wv*16+m16]; LEPE from LDS halo
  const int pix = wv * 16 + m16;
  const int pa = pix >> 3, pb = pix & 7;

  f32x4 lep = *(const f32x4*)&wls[144 + qd * 4];  // bias
#pragma unroll
  for (int di = 0; di < 3; ++di)
#pragma unroll
    for (int dj = 0; dj < 3; ++dj) {
      f32x4 hv = *(const f32x4*)&halo[((pa + di) * 10 + pb + dj) * 20 + qd * 4];
      f32x4 wt4 = *(const f32x4*)&wls[(di * 3 + dj) * 16 + qd * 4];
#pragma unroll
      for (int rr = 0; rr < 4; ++rr) lep[rr] = fmaf(hv[rr], wt4[rr], lep[rr]);
    }

  const int ga = wr * 8 + pa, gb = wc * 8 + pb;
  float4 o = {oacc[0] * inv + lep[0], oacc[1] * inv + lep[1],
              oacc[2] * inv + lep[2], oacc[3] * inv + lep[3]};
  *(float4*)&outp[(((size_t)n * HWD + ga) * HWD + gb) * CIN + h * 16 + qd * 4] = o;
}

extern "C" void kernel_launch(void* const* d_in, const int* in_sizes, int n_in,
                              void* d_out, int out_size, void* d_ws, size_t ws_size,
                              hipStream_t stream) {
  const float* x        = (const float*)d_in[0];
  const float* y        = (const float*)d_in[1];
  const float* w_qkv_x  = (const float*)d_in[2];
  const float* b_qkv_x  = (const float*)d_in[3];
  const float* w_qkv_y  = (const float*)d_in[4];
  const float* b_qkv_y  = (const float*)d_in[5];
  const float* w_lepe_x = (const float*)d_in[6];
  const float* b_lepe_x = (const float*)d_in[7];
  const float* w_lepe_y = (const float*)d_in[8];
  const float* b_lepe_y = (const float*)d_in[9];
  float* out = (float*)d_out;

  const size_t qkv_sz = (size_t)NB * P2 * 64 * COUT;   // bf16 elems
  const size_t xbf_sz = (size_t)NB * P2 * 64 * CIN;    // bf16 elems
  const size_t wt_sz  = (size_t)COUT * CIN;            // bf16 elems
  const size_t win_sz = (size_t)NB * P2 * 128;         // fp32 elems

  ushort_t* qkvx = (ushort_t*)d_ws;
  ushort_t* qkvy = qkvx + qkv_sz;
  ushort_t* xbfx = qkvy + qkv_sz;
  ushort_t* xbfy = xbfx + xbf_sz;
  ushort_t* Wtx  = xbfy + xbf_sz;
  ushort_t* Wty  = Wtx + wt_sz;
  float* qwx = (float*)(Wty + wt_sz);
  float* kwx = qwx + win_sz;
  float* qwy = kwx + win_sz;
  float* kwy = qwy + win_sz;
  int* idxx = (int*)(kwy + win_sz);
  int* idxy = idxx + NB * P2 * 4;

  meanproj_kernel<<<dim3(P2, NB, 2), 256, 0, stream>>>(
      x, y, w_qkv_x, b_qkv_x, w_qkv_y, b_qkv_y, xbfx, xbfy, qwx, kwx, qwy, kwy);
  wt_kernel<<<dim3(3, 2), 128, 0, stream>>>(w_qkv_x, w_qkv_y, Wtx, Wty);
  route_kernel<<<dim3(2, NB), 256, 0, stream>>>(qwx, kwx, qwy, kwy, idxx, idxy);
  qkv_gemm_kernel<<<dim3(196, 3, 2), 256, 0, stream>>>(
      xbfx, xbfy, Wtx, Wty, b_qkv_x, b_qkv_y, qkvx, qkvy);
  attn_kernel<<<dim3(P2, NB, 16), 256, 0, stream>>>(
      qkvx, qkvy, idxx, idxy, w_lepe_x, b_lepe_x, w_lepe_y, b_lepe_y, out);
}

// Round 5
// 231.521 us; speedup vs baseline: 1.0571x; 1.0571x over previous
//
#include <hip/hip_runtime.h>

#define HWD 56
#define NWIN 7
#define P2 49
#define CIN 128
#define COUT 384
#define NB 8
#define SCALE 0.08838834764831843f

typedef __attribute__((ext_vector_type(8))) short bf16x8;
typedef __attribute__((ext_vector_type(4))) float f32x4;
typedef __attribute__((ext_vector_type(8))) unsigned short u16x8;
typedef unsigned short ushort_t;

__device__ inline unsigned short f2bf(float f) {
  unsigned int u = __float_as_uint(f);
  unsigned int r = (u + 0x7fffu + ((u >> 16) & 1u)) >> 16;
  return (unsigned short)r;
}
__device__ inline float bf2f(unsigned short b) {
  return __uint_as_float(((unsigned int)b) << 16);
}

// ---------------- window mean of x + fp32 projection (routing path) + bf16 x emit ----------------
// grid (49, 8, 2), block 256
__global__ __launch_bounds__(256) void meanproj_kernel(
    const float* __restrict__ xin, const float* __restrict__ yin,
    const float* __restrict__ Wx, const float* __restrict__ Bx,
    const float* __restrict__ Wy, const float* __restrict__ By,
    ushort_t* __restrict__ xbfx, ushort_t* __restrict__ xbfy,
    float* __restrict__ qwx, float* __restrict__ kwx,
    float* __restrict__ qwy, float* __restrict__ kwy)
{
  const int p = blockIdx.x, n = blockIdx.y, br = blockIdx.z;
  const float* X  = br ? yin : xin;
  const float* W  = br ? Wy  : Wx;
  const float* Bv = br ? By  : Bx;
  ushort_t* xb = (br ? xbfy : xbfx) + (size_t)(n * P2 + p) * 64 * CIN;
  float* qw = br ? qwy : qwx;
  float* kw = br ? kwy : kwx;

  __shared__ float sm[2][128];
  __shared__ float mxs[128];
  const int t = threadIdx.x;
  const int wr = p / NWIN, wc = p % NWIN;
  const int ch = t & 127, half = t >> 7;

  float s = 0.f;
#pragma unroll 4
  for (int i = 0; i < 32; ++i) {
    int pix = half * 32 + i;
    int a = wr * 8 + (pix >> 3), b = wc * 8 + (pix & 7);
    float v = X[(((size_t)n * HWD + a) * HWD + b) * CIN + ch];
    s += v;
    xb[pix * CIN + ch] = f2bf(v);
  }
  sm[half][ch] = s;
  __syncthreads();
  if (t < 128) mxs[t] = (sm[0][t] + sm[1][t]) * (1.f / 64.f);
  __syncthreads();

  float acc = Bv[t];
#pragma unroll 8
  for (int k = 0; k < 128; ++k) acc = fmaf(mxs[k], W[(size_t)k * COUT + t], acc);
  if (t < 128) qw[(n * P2 + p) * 128 + t] = acc;
  else         kw[(n * P2 + p) * 128 + (t - 128)] = acc;
}

// ---------------- W transpose -> bf16 Wt[cout][k] ----------------
__global__ __launch_bounds__(128) void wt_kernel(
    const float* __restrict__ Wx, const float* __restrict__ Wy,
    ushort_t* __restrict__ Wtx, ushort_t* __restrict__ Wty)
{
  const int br = blockIdx.y;
  const float* W = br ? Wy : Wx;
  ushort_t* Wt = br ? Wty : Wtx;
  const int c = blockIdx.x * 128 + threadIdx.x;
  for (int k8 = 0; k8 < 128; k8 += 8) {
    u16x8 buf;
#pragma unroll
    for (int i = 0; i < 8; ++i) buf[i] = f2bf(W[(size_t)(k8 + i) * COUT + c]);
    *(u16x8*)&Wt[(size_t)c * 128 + k8] = buf;
  }
}

// ---------------- routing: top-4 window indices (fp32) ----------------
__global__ __launch_bounds__(256) void route_kernel(
    const float* __restrict__ qwx, const float* __restrict__ kwx,
    const float* __restrict__ qwy, const float* __restrict__ kwy,
    int* __restrict__ idxx, int* __restrict__ idxy)
{
  const int br = blockIdx.x, n = blockIdx.y;
  const float* qw = br ? qwy : qwx;
  const float* kw = br ? kwy : kwx;
  int* idx = br ? idxy : idxx;

  __shared__ float qs[P2][128];
  __shared__ float ks[P2][128];
  __shared__ float ls[P2][52];
  const int t = threadIdx.x;
  for (int e = t; e < P2 * 128; e += 256) {
    qs[e >> 7][e & 127] = qw[(size_t)n * P2 * 128 + e];
    ks[e >> 7][e & 127] = kw[(size_t)n * P2 * 128 + e];
  }
  __syncthreads();
  for (int pair = t; pair < P2 * P2; pair += 256) {
    int r = pair / P2, j = pair % P2;
    float d = 0.f;
#pragma unroll
    for (int c4 = 0; c4 < 32; ++c4) {
      float4 a = *(const float4*)&qs[r][c4 * 4];
      float4 b = *(const float4*)&ks[j][c4 * 4];
      d = fmaf(a.x, b.x, d); d = fmaf(a.y, b.y, d);
      d = fmaf(a.z, b.z, d); d = fmaf(a.w, b.w, d);
    }
    ls[r][j] = d;
  }
  __syncthreads();
  if (t < P2) {
    int ch[4];
    for (int s = 0; s < 4; ++s) {
      float best = -1e30f; int bi = 0;
      for (int j = 0; j < P2; ++j) {
        bool taken = false;
        for (int u = 0; u < s; ++u) taken = taken || (ch[u] == j);
        if (!taken && ls[t][j] > best) { best = ls[t][j]; bi = j; }
      }
      ch[s] = bi;
      idx[((size_t)n * P2 + t) * 4 + s] = bi;
    }
  }
}

// ---------------- qkv GEMM -> head-blocked tensors ----------------
// Qp/Kp: [win][head 8][pix 64][16ch] (q pre-scaled by SCALE)
// Vc:    [win][head 8][16ch][pix 64]   Vp: [win][head 8][pix 64][16ch]
// grid (196, 3, 2); block 256 = 4 waves
#define AS 136
__global__ __launch_bounds__(256) void qkv_gemm_kernel(
    const ushort_t* __restrict__ xbfx, const ushort_t* __restrict__ xbfy,
    const ushort_t* __restrict__ Wtx, const ushort_t* __restrict__ Wty,
    const float* __restrict__ Bx, const float* __restrict__ By,
    ushort_t* __restrict__ Qpx, ushort_t* __restrict__ Qpy,
    ushort_t* __restrict__ Kpx, ushort_t* __restrict__ Kpy,
    ushort_t* __restrict__ Vcx, ushort_t* __restrict__ Vcy,
    ushort_t* __restrict__ Vpx, ushort_t* __restrict__ Vpy)
{
  const int mt = blockIdx.x, nt = blockIdx.y, br = blockIdx.z;
  const ushort_t* Xb = br ? xbfy : xbfx;
  const ushort_t* Wt = br ? Wty : Wtx;
  const float* Bv = br ? By : Bx;

  __shared__ ushort_t a_s[128 * AS];  // [token][k]
  __shared__ ushort_t b_s[128 * AS];  // [cout][k]

  const int t = threadIdx.x;
#pragma unroll
  for (int it = 0; it < 8; ++it) {
    int row = it * 16 + (t >> 4);
    int e8 = (t & 15) * 8;
    *(u16x8*)&a_s[row * AS + e8] = *(const u16x8*)&Xb[((size_t)mt * 128 + row) * 128 + e8];
    *(u16x8*)&b_s[row * AS + e8] = *(const u16x8*)&Wt[((size_t)nt * 128 + row) * 128 + e8];
  }
  __syncthreads();

  const int wv = t >> 6, wm = wv >> 1, wn = wv & 1;
  const int lane = t & 63, qd = lane >> 4, m16 = lane & 15;

  f32x4 acc[4][4];
#pragma unroll
  for (int i = 0; i < 4; ++i)
#pragma unroll
    for (int j = 0; j < 4; ++j) acc[i][j] = (f32x4){0.f, 0.f, 0.f, 0.f};

#pragma unroll
  for (int ks = 0; ks < 4; ++ks) {
    bf16x8 af[4], bfr[4];
#pragma unroll
    for (int fi = 0; fi < 4; ++fi)
      af[fi] = *(const bf16x8*)&a_s[(wm * 64 + fi * 16 + m16) * AS + ks * 32 + qd * 8];
#pragma unroll
    for (int fj = 0; fj < 4; ++fj)
      bfr[fj] = *(const bf16x8*)&b_s[(wn * 64 + fj * 16 + m16) * AS + ks * 32 + qd * 8];
    // D = W x X^T : m=cout (reg rows), n=token (lane col)
#pragma unroll
    for (int fi = 0; fi < 4; ++fi)
#pragma unroll
      for (int fj = 0; fj < 4; ++fj)
        acc[fi][fj] = __builtin_amdgcn_mfma_f32_16x16x32_bf16(bfr[fj], af[fi], acc[fi][fj], 0, 0, 0);
  }

  const int gw = mt * 2 + wm;   // global window
  const float scl = (nt == 0) ? SCALE : 1.0f;

  if (nt < 2) {
    ushort_t* dst = (nt == 0) ? (br ? Qpy : Qpx) : (br ? Kpy : Kpx);
#pragma unroll
    for (int fj = 0; fj < 4; ++fj) {
      int lch = wn * 64 + fj * 16 + qd * 4;        // 0..127 within q/k block
      int h = lch >> 4, chlo = lch & 15;
      float4 b4 = *(const float4*)&Bv[nt * 128 + lch];
#pragma unroll
      for (int fi = 0; fi < 4; ++fi) {
        int pix = fi * 16 + m16;
        ushort4 st = {f2bf((acc[fi][fj][0] + b4.x) * scl), f2bf((acc[fi][fj][1] + b4.y) * scl),
                      f2bf((acc[fi][fj][2] + b4.z) * scl), f2bf((acc[fi][fj][3] + b4.w) * scl)};
        *(ushort4*)&dst[(((size_t)gw * 8 + h) * 64 + pix) * 16 + chlo] = st;
      }
    }
  } else {
    ushort_t* dvp = br ? Vpy : Vpx;
    ushort_t* dvc = br ? Vcy : Vcx;
#pragma unroll
    for (int fj = 0; fj < 4; ++fj) {
      int lch = wn * 64 + fj * 16 + qd * 4;
      int h = lch >> 4, chlo = lch & 15;
      float4 b4 = *(const float4*)&Bv[256 + lch];
#pragma unroll
      for (int fi = 0; fi < 4; ++fi) {
        int pix = fi * 16 + m16;
        float v0 = acc[fi][fj][0] + b4.x, v1 = acc[fi][fj][1] + b4.y;
        float v2 = acc[fi][fj][2] + b4.z, v3 = acc[fi][fj][3] + b4.w;
        ushort4 st = {f2bf(v0), f2bf(v1), f2bf(v2), f2bf(v3)};
        *(ushort4*)&dvp[(((size_t)gw * 8 + h) * 64 + pix) * 16 + chlo] = st;
        size_t cb = (((size_t)gw * 8 + h) * 16 + chlo) * 64 + pix;
        dvc[cb]        = st.x;
        dvc[cb + 64]   = st.y;
        dvc[cb + 128]  = st.z;
        dvc[cb + 192]  = st.w;
      }
    }
  }
}

// ---------------- fused attention + LEPE; all MFMA operands direct-global ----------------
// grid (49, 8, 16): z = head*2 + dir; block 256 = 4 waves, wave wv owns q-rows [16wv,16wv+16)
__global__ __launch_bounds__(256) void attn_kernel(
    const ushort_t* __restrict__ Qpx, const ushort_t* __restrict__ Qpy,
    const ushort_t* __restrict__ Kpx, const ushort_t* __restrict__ Kpy,
    const ushort_t* __restrict__ Vcx, const ushort_t* __restrict__ Vcy,
    const ushort_t* __restrict__ Vpx, const ushort_t* __restrict__ Vpy,
    const int* __restrict__ idxx, const int* __restrict__ idxy,
    const float* __restrict__ wlx, const float* __restrict__ blx,
    const float* __restrict__ wly, const float* __restrict__ bly,
    float* __restrict__ dout)
{
  const int p = blockIdx.x, n = blockIdx.y, z = blockIdx.z;
  const int h = z >> 1, dir = z & 1;
  const ushort_t* Qp = dir ? Qpy : Qpx;
  const ushort_t* Kp = dir ? Kpy : Kpx;
  const ushort_t* Vc = dir ? Vcx : Vcy;   // cross-branch V
  const ushort_t* Vp = dir ? Vpx : Vpy;
  const int* idxK = dir ? idxy : idxx;
  const int* idxV = dir ? idxx : idxy;
  const float* wl = dir ? wlx : wly;      // dir0 writes out_y -> lepe_y
  const float* bl = dir ? blx : bly;
  const size_t OUTHALF = (size_t)NB * HWD * HWD * CIN;
  float* outp = dout + (dir ? 0 : OUTHALF);

  __shared__ float halo[100 * 20];   // [10x10 pix][16ch fp32], stride 20
  __shared__ float wls[160];         // [tap 0..8][16ch] + [bias][16ch]

  const int t = threadIdx.x;
  const int wv = t >> 6, r = t & 63;
  const int wr = p / NWIN, wc = p % NWIN;

  const int4 kidx = *(const int4*)&idxK[((size_t)n * P2 + p) * 4];
  const int4 vidx = *(const int4*)&idxV[((size_t)n * P2 + p) * 4];
  const int kw4[4] = {kidx.x, kidx.y, kidx.z, kidx.w};
  const int vw4[4] = {vidx.x, vidx.y, vidx.z, vidx.w};

  // LEPE halo: 10x10 pixels x 16ch fp32 (zero outside image) from Vp (this dir's out branch V)
  if (t < 200) {
    int hp = t >> 1, hf = t & 1;
    int A = wr * 8 - 1 + (int)((unsigned)hp / 10u);
    int B = wc * 8 - 1 + (int)((unsigned)hp % 10u);
    f32x4 f0 = {0.f, 0.f, 0.f, 0.f}, f1 = {0.f, 0.f, 0.f, 0.f};
    if ((unsigned)A < (unsigned)HWD && (unsigned)B < (unsigned)HWD) {
      int gw = (A >> 3) * NWIN + (B >> 3);
      int pix = (A & 7) * 8 + (B & 7);
      u16x8 vv = *(const u16x8*)&Vp[(((size_t)(n * P2 + gw) * 8 + h) * 64 + pix) * 16 + hf * 8];
      f0[0] = bf2f(vv[0]); f0[1] = bf2f(vv[1]); f0[2] = bf2f(vv[2]); f0[3] = bf2f(vv[3]);
      f1[0] = bf2f(vv[4]); f1[1] = bf2f(vv[5]); f1[2] = bf2f(vv[6]); f1[3] = bf2f(vv[7]);
    }
    *(f32x4*)&halo[hp * 20 + hf * 8] = f0;
    *(f32x4*)&halo[hp * 20 + hf * 8 + 4] = f1;
  }
  if (t < 160) {
    int row = t >> 4, c = t & 15;
    wls[t] = (row < 9) ? wl[(h * 16 + c) * 9 + row] : bl[h * 16 + c];
  }

  const int qd = r >> 4, m16 = r & 15;
  const f32x4 zf = {0.f, 0.f, 0.f, 0.f};

  // Q A^T-frag direct from global (pre-scaled by SCALE in gemm)
  const ushort_t* Qw = Qp + ((size_t)(n * P2 + p) * 8 + h) * 1024;
  bf16x8 qf = (bf16x8)(short)0;
  if (qd < 2) qf = *(const bf16x8*)&Qw[(wv * 16 + m16) * 16 + qd * 8];

  // Phase 1: scores S^T = K x Q^T; K frags direct from global
  f32x4 s[8][2];
#pragma unroll
  for (int c = 0; c < 8; ++c) {
    const ushort_t* Kw = Kp + ((size_t)(n * P2 + kw4[c >> 1]) * 8 + h) * 1024;
    int lk = (c & 1) * 32;
    bf16x8 kf0 = (bf16x8)(short)0, kf1 = (bf16x8)(short)0;
    if (qd < 2) {
      kf0 = *(const bf16x8*)&Kw[(lk + m16) * 16 + qd * 8];
      kf1 = *(const bf16x8*)&Kw[(lk + 16 + m16) * 16 + qd * 8];
    }
    s[c][0] = __builtin_amdgcn_mfma_f32_16x16x32_bf16(kf0, qf, zf, 0, 0, 0);
    s[c][1] = __builtin_amdgcn_mfma_f32_16x16x32_bf16(kf1, qf, zf, 0, 0, 0);
  }

  // Phase 2: single-pass softmax over 256 keys (lane-local rows)
  float m = -1e30f;
#pragma unroll
  for (int c = 0; c < 8; ++c)
#pragma unroll
    for (int hh = 0; hh < 2; ++hh)
#pragma unroll
      for (int rr = 0; rr < 4; ++rr) m = fmaxf(m, s[c][hh][rr]);
  m = fmaxf(m, __shfl_xor(m, 16));
  m = fmaxf(m, __shfl_xor(m, 32));
  float l = 0.f;
#pragma unroll
  for (int c = 0; c < 8; ++c)
#pragma unroll
    for (int hh = 0; hh < 2; ++hh)
#pragma unroll
      for (int rr = 0; rr < 4; ++rr) {
        float e = __expf(s[c][hh][rr] - m);
        s[c][hh][rr] = e;
        l += e;
      }
  l += __shfl_xor(l, 16);
  l += __shfl_xor(l, 32);
  const float inv = 1.f / l;

  // Phase 3: O^T = V^T x P^T; V^T frags direct from global (Vc channel-major)
  f32x4 oacc = {0.f, 0.f, 0.f, 0.f};
#pragma unroll
  for (int c = 0; c < 8; ++c) {
    int pk[4];
#pragma unroll
    for (int rr = 0; rr < 4; ++rr)
      pk[rr] = (int)((unsigned int)f2bf(s[c][0][rr]) | ((unsigned int)f2bf(s[c][1][rr]) << 16));
    u16x8 pfu;
#pragma unroll
    for (int j = 0; j < 8; ++j) {
      int srcl = (((qd & 1) * 2 + (j >> 2)) << 4) + m16;
      int w = __shfl(pk[j & 3], srcl);
      pfu[j] = (qd < 2) ? (unsigned short)(w & 0xffff) : (unsigned short)((unsigned)w >> 16);
    }
    const ushort_t* Vw = Vc + ((size_t)(n * P2 + vw4[c >> 1]) * 8 + h) * 1024;
    bf16x8 vtf = *(const bf16x8*)&Vw[m16 * 64 + (c & 1) * 32 + qd * 8];
    oacc = __builtin_amdgcn_mfma_f32_16x16x32_bf16(vtf, *(bf16x8*)&pfu, oacc, 0, 0, 0);
  }

  __syncthreads();  // halo + wls ready (staged at kernel top)

  // Epilogue: lane = O^T[ch=h*16+qd*4+rr][qrow=wv*16+m16]; LEPE from LDS halo
  const int pix = wv * 16 + m16;
  const int pa = pix >> 3, pb = pix & 7;

  f32x4 lep = *(const f32x4*)&wls[144 + qd * 4];  // bias
#pragma unroll
  for (int di = 0; di < 3; ++di)
#pragma unroll
    for (int dj = 0; dj < 3; ++dj) {
      f32x4 hv = *(const f32x4*)&halo[((pa + di) * 10 + pb + dj) * 20 + qd * 4];
      f32x4 wt4 = *(const f32x4*)&wls[(di * 3 + dj) * 16 + qd * 4];
#pragma unroll
      for (int rr = 0; rr < 4; ++rr) lep[rr] = fmaf(hv[rr], wt4[rr], lep[rr]);
    }

  const int ga = wr * 8 + pa, gb = wc * 8 + pb;
  float4 o = {oacc[0] * inv + lep[0], oacc[1] * inv + lep[1],
              oacc[2] * inv + lep[2], oacc[3] * inv + lep[3]};
  *(float4*)&outp[(((size_t)n * HWD + ga) * HWD + gb) * CIN + h * 16 + qd * 4] = o;
}

extern "C" void kernel_launch(void* const* d_in, const int* in_sizes, int n_in,
                              void* d_out, int out_size, void* d_ws, size_t ws_size,
                              hipStream_t stream) {
  const float* x        = (const float*)d_in[0];
  const float* y        = (const float*)d_in[1];
  const float* w_qkv_x  = (const float*)d_in[2];
  const float* b_qkv_x  = (const float*)d_in[3];
  const float* w_qkv_y  = (const float*)d_in[4];
  const float* b_qkv_y  = (const float*)d_in[5];
  const float* w_lepe_x = (const float*)d_in[6];
  const float* b_lepe_x = (const float*)d_in[7];
  const float* w_lepe_y = (const float*)d_in[8];
  const float* b_lepe_y = (const float*)d_in[9];
  float* out = (float*)d_out;

  const size_t hb_sz  = (size_t)NB * P2 * 8 * 64 * 16;  // head-blocked tensor, bf16 elems
  const size_t xbf_sz = (size_t)NB * P2 * 64 * CIN;
  const size_t wt_sz  = (size_t)COUT * CIN;
  const size_t win_sz = (size_t)NB * P2 * 128;

  ushort_t* base = (ushort_t*)d_ws;
  ushort_t* Qpx = base;            ushort_t* Qpy = Qpx + hb_sz;
  ushort_t* Kpx = Qpy + hb_sz;     ushort_t* Kpy = Kpx + hb_sz;
  ushort_t* Vcx = Kpy + hb_sz;     ushort_t* Vcy = Vcx + hb_sz;
  ushort_t* Vpx = Vcy + hb_sz;     ushort_t* Vpy = Vpx + hb_sz;
  ushort_t* xbfx = Vpy + hb_sz;    ushort_t* xbfy = xbfx + xbf_sz;
  ushort_t* Wtx  = xbfy + xbf_sz;  ushort_t* Wty  = Wtx + wt_sz;
  float* qwx = (float*)(Wty + wt_sz);
  float* kwx = qwx + win_sz;
  float* qwy = kwx + win_sz;
  float* kwy = qwy + win_sz;
  int* idxx = (int*)(kwy + win_sz);
  int* idxy = idxx + NB * P2 * 4;

  meanproj_kernel<<<dim3(P2, NB, 2), 256, 0, stream>>>(
      x, y, w_qkv_x, b_qkv_x, w_qkv_y, b_qkv_y, xbfx, xbfy, qwx, kwx, qwy, kwy);
  wt_kernel<<<dim3(3, 2), 128, 0, stream>>>(w_qkv_x, w_qkv_y, Wtx, Wty);
  route_kernel<<<dim3(2, NB), 256, 0, stream>>>(qwx, kwx, qwy, kwy, idxx, idxy);
  qkv_gemm_kernel<<<dim3(196, 3, 2), 256, 0, stream>>>(
      xbfx, xbfy, Wtx, Wty, b_qkv_x, b_qkv_y,
      Qpx, Qpy, Kpx, Kpy, Vcx, Vcy, Vpx, Vpy);
  attn_kernel<<<dim3(P2, NB, 16), 256, 0, stream>>>(
      Qpx, Qpy, Kpx, Kpy, Vcx, Vcy, Vpx, Vpy, idxx, idxy,
      w_lepe_x, b_lepe_x, w_lepe_y, b_lepe_y, out);
}

// Round 6
// 220.960 us; speedup vs baseline: 1.1076x; 1.0478x over previous
//
#include <hip/hip_runtime.h>

#define HWD 56
#define NWIN 7
#define P2 49
#define CIN 128
#define COUT 384
#define NB 8
#define SCALE 0.08838834764831843f

typedef __attribute__((ext_vector_type(8))) short bf16x8;
typedef __attribute__((ext_vector_type(4))) float f32x4;
typedef __attribute__((ext_vector_type(8))) unsigned short u16x8;
typedef unsigned short ushort_t;

#if __has_builtin(__builtin_amdgcn_mfma_f32_16x16x16bf16_1k)
#define HAVE_MFMA16 1
typedef __attribute__((ext_vector_type(4))) short bf16x4;
#endif

__device__ inline unsigned short f2bf(float f) {
  unsigned int u = __float_as_uint(f);
  unsigned int r = (u + 0x7fffu + ((u >> 16) & 1u)) >> 16;
  return (unsigned short)r;
}
__device__ inline float bf2f(unsigned short b) {
  return __uint_as_float(((unsigned int)b) << 16);
}

// ---------------- mean(x) + fp32 routing projection + bf16 x emit + Wt convert ----------------
// grid (8, 49, 2): x=n (XCD affinity), y=p, z=br; block 256
__global__ __launch_bounds__(256) void meanproj_kernel(
    const float* __restrict__ xin, const float* __restrict__ yin,
    const float* __restrict__ Wx, const float* __restrict__ Bx,
    const float* __restrict__ Wy, const float* __restrict__ By,
    ushort_t* __restrict__ xbfx, ushort_t* __restrict__ xbfy,
    ushort_t* __restrict__ Wtx, ushort_t* __restrict__ Wty,
    float* __restrict__ qwx, float* __restrict__ kwx,
    float* __restrict__ qwy, float* __restrict__ kwy)
{
  const int n = blockIdx.x, p = blockIdx.y, br = blockIdx.z;
  const float* X  = br ? yin : xin;
  const float* W  = br ? Wy  : Wx;
  const float* Bv = br ? By  : Bx;
  ushort_t* xb = (br ? xbfy : xbfx) + (size_t)(n * P2 + p) * 64 * CIN;
  ushort_t* Wt = br ? Wty : Wtx;
  float* qw = br ? qwy : qwx;
  float* kw = br ? kwy : kwx;

  __shared__ float smf[8][132];
  __shared__ float mxs[128];
  const int t = threadIdx.x;
  const int wr = p / NWIN, wc = p % NWIN;
  const int ch4 = (t & 31) * 4, pg = t >> 5;   // pixel-group = image row within window

  const float* Xrow = X + (((size_t)n * HWD + wr * 8 + pg) * HWD + wc * 8) * CIN;
  float4 s4 = {0.f, 0.f, 0.f, 0.f};
#pragma unroll
  for (int i = 0; i < 8; ++i) {
    float4 v = *(const float4*)&Xrow[i * CIN + ch4];
    s4.x += v.x; s4.y += v.y; s4.z += v.z; s4.w += v.w;
    ushort4 o = {f2bf(v.x), f2bf(v.y), f2bf(v.z), f2bf(v.w)};
    *(ushort4*)&xb[(pg * 8 + i) * CIN + ch4] = o;
  }
  *(float4*)&smf[pg][ch4] = s4;
  __syncthreads();
  if (t < 128) {
    float s = 0.f;
#pragma unroll
    for (int g = 0; g < 8; ++g) s += smf[g][t];
    mxs[t] = s * (1.f / 64.f);
  }
  __syncthreads();

  // fp32 exact projection for routing ordering (cout = t, 0..255 covers q|k)
  float acc = Bv[t];
#pragma unroll 8
  for (int k = 0; k < 128; ++k) acc = fmaf(mxs[k], W[(size_t)k * COUT + t], acc);
  if (t < 128) qw[(n * P2 + p) * 128 + t] = acc;
  else         kw[(n * P2 + p) * 128 + (t - 128)] = acc;

  // embedded Wt conversion: p==0 blocks each convert couts [n*48, n*48+48)
  if (p == 0) {
    for (int e = t; e < 48 * 128; e += 256) {
      int c = n * 48 + (e >> 7), k = e & 127;
      Wt[(size_t)c * 128 + k] = f2bf(W[(size_t)k * COUT + c]);
    }
  }
}

// ---------------- routing: top-4 window indices (fp32, ballot argmax) ----------------
// grid (2, 8), block 256
__global__ __launch_bounds__(256) void route_kernel(
    const float* __restrict__ qwx, const float* __restrict__ kwx,
    const float* __restrict__ qwy, const float* __restrict__ kwy,
    int* __restrict__ idxx, int* __restrict__ idxy)
{
  const int br = blockIdx.x, n = blockIdx.y;
  const float* qw = br ? qwy : qwx;
  const float* kw = br ? kwy : kwx;
  int* idx = br ? idxy : idxx;

  __shared__ float qs[P2][128];
  __shared__ float ks[P2][128];
  __shared__ float ls[P2][52];
  const int t = threadIdx.x;
  for (int e = t; e < P2 * 128; e += 256) {
    qs[e >> 7][e & 127] = qw[(size_t)n * P2 * 128 + e];
    ks[e >> 7][e & 127] = kw[(size_t)n * P2 * 128 + e];
  }
  __syncthreads();
  for (int pair = t; pair < P2 * P2; pair += 256) {
    int r = pair / P2, j = pair % P2;
    float d = 0.f;
#pragma unroll
    for (int c4 = 0; c4 < 32; ++c4) {
      float4 a = *(const float4*)&qs[r][c4 * 4];
      float4 b = *(const float4*)&ks[j][c4 * 4];
      d = fmaf(a.x, b.x, d); d = fmaf(a.y, b.y, d);
      d = fmaf(a.z, b.z, d); d = fmaf(a.w, b.w, d);
    }
    ls[r][j] = d;  // positive scale is monotone: ordering identical
  }
  __syncthreads();
  const int lane = t & 63, wv = t >> 6;
  for (int row = wv; row < P2; row += 4) {
    float v = (lane < P2) ? ls[row][lane] : -1e30f;
    int out4[4];
#pragma unroll
    for (int sel = 0; sel < 4; ++sel) {
      float m = v;
#pragma unroll
      for (int msk = 1; msk < 64; msk <<= 1) m = fmaxf(m, __shfl_xor(m, msk));
      unsigned long long b = __ballot(v == m);
      int bi = __ffsll((unsigned long long)b) - 1;  // lowest index on ties (jax top_k)
      out4[sel] = bi;
      if (lane == bi) v = -1e30f;
    }
    if (lane == 0) {
      int4 o = {out4[0], out4[1], out4[2], out4[3]};
      *(int4*)&idx[((size_t)n * P2 + row) * 4] = o;
    }
  }
}

// ---------------- qkv GEMM per window: A in LDS, B (Wt) direct global ----------------
// Qp/Kp: [win][head 8][pix 64][16ch] (q pre-scaled); Vc: [win][head][16ch][pix]; Vp like Qp.
// grid (8, 49, 2): x=n (XCD), y=p, z=br; block 256 = 4 waves; wave wv owns couts [96wv, 96wv+96)
#define XS 136
__global__ __launch_bounds__(256) void qkv_gemm_kernel(
    const ushort_t* __restrict__ xbfx, const ushort_t* __restrict__ xbfy,
    const ushort_t* __restrict__ Wtx, const ushort_t* __restrict__ Wty,
    const float* __restrict__ Bx, const float* __restrict__ By,
    ushort_t* __restrict__ Qpx, ushort_t* __restrict__ Qpy,
    ushort_t* __restrict__ Kpx, ushort_t* __restrict__ Kpy,
    ushort_t* __restrict__ Vcx, ushort_t* __restrict__ Vcy,
    ushort_t* __restrict__ Vpx, ushort_t* __restrict__ Vpy)
{
  const int n = blockIdx.x, p = blockIdx.y, br = blockIdx.z;
  const ushort_t* Xw = (br ? xbfy : xbfx) + (size_t)(n * P2 + p) * 64 * CIN;
  const ushort_t* Wt = br ? Wty : Wtx;
  const float* Bv = br ? By : Bx;
  ushort_t* Qp = br ? Qpy : Qpx;
  ushort_t* Kp = br ? Kpy : Kpx;
  ushort_t* Vc = br ? Vcy : Vcx;
  ushort_t* Vp = br ? Vpy : Vpx;

  __shared__ ushort_t a_s[64 * XS];   // [token][k]

  const int t = threadIdx.x;
#pragma unroll
  for (int it = 0; it < 4; ++it) {
    int e = it * 256 + t;
    int row = e >> 4, c8 = (e & 15) * 8;
    *(u16x8*)&a_s[row * XS + c8] = *(const u16x8*)&Xw[row * 128 + c8];
  }
  __syncthreads();

  const int wv = t >> 6, lane = t & 63, qd = lane >> 4, m16 = lane & 15;
  const ushort_t* Wb = Wt + (size_t)(wv * 96) * 128;

  f32x4 acc[4][6];
#pragma unroll
  for (int i = 0; i < 4; ++i)
#pragma unroll
    for (int j = 0; j < 6; ++j) acc[i][j] = (f32x4){0.f, 0.f, 0.f, 0.f};

#pragma unroll
  for (int ks = 0; ks < 4; ++ks) {
    bf16x8 af[4], bfw[6];
#pragma unroll
    for (int fi = 0; fi < 4; ++fi)
      af[fi] = *(const bf16x8*)&a_s[(fi * 16 + m16) * XS + ks * 32 + qd * 8];
#pragma unroll
    for (int fj = 0; fj < 6; ++fj)
      bfw[fj] = *(const bf16x8*)&Wb[(size_t)(fj * 16 + m16) * 128 + ks * 32 + qd * 8];
    // D = W x X^T : m=cout (reg rows), n=token (lane col)
#pragma unroll
    for (int fi = 0; fi < 4; ++fi)
#pragma unroll
      for (int fj = 0; fj < 6; ++fj)
        acc[fi][fj] = __builtin_amdgcn_mfma_f32_16x16x32_bf16(bfw[fj], af[fi], acc[fi][fj], 0, 0, 0);
  }

  const size_t wb = (size_t)(n * P2 + p) * 8;   // window base (heads)
#pragma unroll
  for (int fj = 0; fj < 6; ++fj) {
    const int ch = wv * 96 + fj * 16 + qd * 4;  // global cout (frag spans one tensor)
    float4 b4 = *(const float4*)&Bv[ch];
    const int isQ = ch < 128, isK = (ch >= 128) && (ch < 256);
    const float scl = isQ ? SCALE : 1.0f;
    const int lch = ch & 127, h = lch >> 4, chlo = lch & 15;
#pragma unroll
    for (int fi = 0; fi < 4; ++fi) {
      int pix = fi * 16 + m16;
      float v0 = (acc[fi][fj][0] + b4.x) * scl, v1 = (acc[fi][fj][1] + b4.y) * scl;
      float v2 = (acc[fi][fj][2] + b4.z) * scl, v3 = (acc[fi][fj][3] + b4.w) * scl;
      ushort4 st = {f2bf(v0), f2bf(v1), f2bf(v2), f2bf(v3)};
      if (isQ) {
        *(ushort4*)&Qp[((wb + h) * 64 + pix) * 16 + chlo] = st;
      } else if (isK) {
        *(ushort4*)&Kp[((wb + h) * 64 + pix) * 16 + chlo] = st;
      } else {
        *(ushort4*)&Vp[((wb + h) * 64 + pix) * 16 + chlo] = st;
        size_t cb = ((wb + h) * 16 + chlo) * 64 + pix;
        Vc[cb] = st.x; Vc[cb + 64] = st.y; Vc[cb + 128] = st.z; Vc[cb + 192] = st.w;
      }
    }
  }
}

// ---------------- fused attention + LEPE; MFMA operands direct-global ----------------
// grid (8, 49, 16): x=n (XCD), y=p, z=head*2+dir; block 256 = 4 waves (q-row tiles)
__global__ __launch_bounds__(256) void attn_kernel(
    const ushort_t* __restrict__ Qpx, const ushort_t* __restrict__ Qpy,
    const ushort_t* __restrict__ Kpx, const ushort_t* __restrict__ Kpy,
    const ushort_t* __restrict__ Vcx, const ushort_t* __restrict__ Vcy,
    const ushort_t* __restrict__ Vpx, const ushort_t* __restrict__ Vpy,
    const int* __restrict__ idxx, const int* __restrict__ idxy,
    const float* __restrict__ wlx, const float* __restrict__ blx,
    const float* __restrict__ wly, const float* __restrict__ bly,
    float* __restrict__ dout)
{
  const int n = blockIdx.x, p = blockIdx.y, z = blockIdx.z;
  const int h = z >> 1, dir = z & 1;
  const ushort_t* Qp = dir ? Qpy : Qpx;
  const ushort_t* Kp = dir ? Kpy : Kpx;
  const ushort_t* Vc = dir ? Vcx : Vcy;   // cross-branch V
  const ushort_t* Vp = dir ? Vpx : Vpy;
  const int* idxK = dir ? idxy : idxx;
  const int* idxV = dir ? idxx : idxy;
  const float* wl = dir ? wlx : wly;      // dir0 writes out_y -> lepe_y
  const float* bl = dir ? blx : bly;
  const size_t OUTHALF = (size_t)NB * HWD * HWD * CIN;
  float* outp = dout + (dir ? 0 : OUTHALF);

  __shared__ float halo[100 * 20];   // [10x10 pix][16ch fp32], stride 20
  __shared__ float wls[160];         // taps 0..8 x16ch + bias x16ch

  const int t = threadIdx.x;
  const int wv = t >> 6;
  const int wr = p / NWIN, wc = p % NWIN;

  const int4 kidx = *(const int4*)&idxK[((size_t)n * P2 + p) * 4];
  const int4 vidx = *(const int4*)&idxV[((size_t)n * P2 + p) * 4];
  const int kw4[4] = {kidx.x, kidx.y, kidx.z, kidx.w};
  const int vw4[4] = {vidx.x, vidx.y, vidx.z, vidx.w};

  // LEPE halo: 10x10 x 16ch fp32 (zero outside)
  if (t < 200) {
    int hp = t >> 1, hf = t & 1;
    int A = wr * 8 - 1 + (int)((unsigned)hp / 10u);
    int B = wc * 8 - 1 + (int)((unsigned)hp % 10u);
    f32x4 f0 = {0.f, 0.f, 0.f, 0.f}, f1 = {0.f, 0.f, 0.f, 0.f};
    if ((unsigned)A < (unsigned)HWD && (unsigned)B < (unsigned)HWD) {
      int gw = (A >> 3) * NWIN + (B >> 3);
      int pix = (A & 7) * 8 + (B & 7);
      u16x8 vv = *(const u16x8*)&Vp[(((size_t)(n * P2 + gw) * 8 + h) * 64 + pix) * 16 + hf * 8];
      f0[0] = bf2f(vv[0]); f0[1] = bf2f(vv[1]); f0[2] = bf2f(vv[2]); f0[3] = bf2f(vv[3]);
      f1[0] = bf2f(vv[4]); f1[1] = bf2f(vv[5]); f1[2] = bf2f(vv[6]); f1[3] = bf2f(vv[7]);
    }
    *(f32x4*)&halo[hp * 20 + hf * 8] = f0;
    *(f32x4*)&halo[hp * 20 + hf * 8 + 4] = f1;
  }
  if (t < 160) {
    int row = t >> 4, c = t & 15;
    wls[t] = (row < 9) ? wl[(h * 16 + c) * 9 + row] : bl[h * 16 + c];
  }

  const int lane = t & 63, qd = lane >> 4, m16 = lane & 15;
  const f32x4 zf = {0.f, 0.f, 0.f, 0.f};
  const ushort_t* Qw = Qp + ((size_t)(n * P2 + p) * 8 + h) * 1024;

  // Phase 1: S^T = K x Q^T (C: col=qrow m16, reg row=key qd*4+rr)
  f32x4 s[8][2];
#if HAVE_MFMA16
  bf16x4 qf = *(const bf16x4*)&Qw[(wv * 16 + m16) * 16 + qd * 4];
#pragma unroll
  for (int c = 0; c < 8; ++c) {
    const ushort_t* Kw = Kp + ((size_t)(n * P2 + kw4[c >> 1]) * 8 + h) * 1024;
    int lk = (c & 1) * 32;
    bf16x4 kf0 = *(const bf16x4*)&Kw[(lk + m16) * 16 + qd * 4];
    bf16x4 kf1 = *(const bf16x4*)&Kw[(lk + 16 + m16) * 16 + qd * 4];
    s[c][0] = __builtin_amdgcn_mfma_f32_16x16x16bf16_1k(kf0, qf, zf, 0, 0, 0);
    s[c][1] = __builtin_amdgcn_mfma_f32_16x16x16bf16_1k(kf1, qf, zf, 0, 0, 0);
  }
#else
  bf16x8 qf = (bf16x8)(short)0;
  if (qd < 2) qf = *(const bf16x8*)&Qw[(wv * 16 + m16) * 16 + qd * 8];
#pragma unroll
  for (int c = 0; c < 8; ++c) {
    const ushort_t* Kw = Kp + ((size_t)(n * P2 + kw4[c >> 1]) * 8 + h) * 1024;
    int lk = (c & 1) * 32;
    bf16x8 kf0 = (bf16x8)(short)0, kf1 = (bf16x8)(short)0;
    if (qd < 2) {
      kf0 = *(const bf16x8*)&Kw[(lk + m16) * 16 + qd * 8];
      kf1 = *(const bf16x8*)&Kw[(lk + 16 + m16) * 16 + qd * 8];
    }
    s[c][0] = __builtin_amdgcn_mfma_f32_16x16x32_bf16(kf0, qf, zf, 0, 0, 0);
    s[c][1] = __builtin_amdgcn_mfma_f32_16x16x32_bf16(kf1, qf, zf, 0, 0, 0);
  }
#endif

  // Phase 2: single-pass softmax over 256 keys (lane-local per q-row)
  float m = -1e30f;
#pragma unroll
  for (int c = 0; c < 8; ++c)
#pragma unroll
    for (int hh = 0; hh < 2; ++hh)
#pragma unroll
      for (int rr = 0; rr < 4; ++rr) m = fmaxf(m, s[c][hh][rr]);
  m = fmaxf(m, __shfl_xor(m, 16));
  m = fmaxf(m, __shfl_xor(m, 32));
  float l = 0.f;
#pragma unroll
  for (int c = 0; c < 8; ++c)
#pragma unroll
    for (int hh = 0; hh < 2; ++hh)
#pragma unroll
      for (int rr = 0; rr < 4; ++rr) {
        float e = __expf(s[c][hh][rr] - m);
        s[c][hh][rr] = e;
        l += e;
      }
  l += __shfl_xor(l, 16);
  l += __shfl_xor(l, 32);
  const float inv = 1.f / l;

  // Phase 3: O^T = V^T x P^T
  f32x4 oacc = {0.f, 0.f, 0.f, 0.f};
#pragma unroll
  for (int c = 0; c < 8; ++c) {
    int pk[4];
#pragma unroll
    for (int rr = 0; rr < 4; ++rr)
      pk[rr] = (int)((unsigned int)f2bf(s[c][0][rr]) | ((unsigned int)f2bf(s[c][1][rr]) << 16));
    u16x8 pfu;
#pragma unroll
    for (int j = 0; j < 8; ++j) {
      int srcl = (((qd & 1) * 2 + (j >> 2)) << 4) + m16;
      int w = __shfl(pk[j & 3], srcl);
      pfu[j] = (qd < 2) ? (unsigned short)(w & 0xffff) : (unsigned short)((unsigned)w >> 16);
    }
    const ushort_t* Vw = Vc + ((size_t)(n * P2 + vw4[c >> 1]) * 8 + h) * 1024;
    bf16x8 vtf = *(const bf16x8*)&Vw[m16 * 64 + (c & 1) * 32 + qd * 8];
    oacc = __builtin_amdgcn_mfma_f32_16x16x32_bf16(vtf, *(bf16x8*)&pfu, oacc, 0, 0, 0);
  }

  __syncthreads();  // halo + wls visibility

  const int pix = wv * 16 + m16;
  const int pa = pix >> 3, pb = pix & 7;

  f32x4 lep = *(const f32x4*)&wls[144 + qd * 4];
#pragma unroll
  for (int di = 0; di < 3; ++di)
#pragma unroll
    for (int dj = 0; dj < 3; ++dj) {
      f32x4 hv = *(const f32x4*)&halo[((pa + di) * 10 + pb + dj) * 20 + qd * 4];
      f32x4 wt4 = *(const f32x4*)&wls[(di * 3 + dj) * 16 + qd * 4];
#pragma unroll
      for (int rr = 0; rr < 4; ++rr) lep[rr] = fmaf(hv[rr], wt4[rr], lep[rr]);
    }

  const int ga = wr * 8 + pa, gb = wc * 8 + pb;
  float4 o = {oacc[0] * inv + lep[0], oacc[1] * inv + lep[1],
              oacc[2] * inv + lep[2], oacc[3] * inv + lep[3]};
  *(float4*)&outp[(((size_t)n * HWD + ga) * HWD + gb) * CIN + h * 16 + qd * 4] = o;
}

extern "C" void kernel_launch(void* const* d_in, const int* in_sizes, int n_in,
                              void* d_out, int out_size, void* d_ws, size_t ws_size,
                              hipStream_t stream) {
  const float* x        = (const float*)d_in[0];
  const float* y        = (const float*)d_in[1];
  const float* w_qkv_x  = (const float*)d_in[2];
  const float* b_qkv_x  = (const float*)d_in[3];
  const float* w_qkv_y  = (const float*)d_in[4];
  const float* b_qkv_y  = (const float*)d_in[5];
  const float* w_lepe_x = (const float*)d_in[6];
  const float* b_lepe_x = (const float*)d_in[7];
  const float* w_lepe_y = (const float*)d_in[8];
  const float* b_lepe_y = (const float*)d_in[9];
  float* out = (float*)d_out;

  const size_t hb_sz  = (size_t)NB * P2 * 8 * 64 * 16;  // head-blocked tensor, bf16 elems
  const size_t xbf_sz = (size_t)NB * P2 * 64 * CIN;
  const size_t wt_sz  = (size_t)COUT * CIN;
  const size_t win_sz = (size_t)NB * P2 * 128;

  ushort_t* base = (ushort_t*)d_ws;
  ushort_t* Qpx = base;            ushort_t* Qpy = Qpx + hb_sz;
  ushort_t* Kpx = Qpy + hb_sz;     ushort_t* Kpy = Kpx + hb_sz;
  ushort_t* Vcx = Kpy + hb_sz;     ushort_t* Vcy = Vcx + hb_sz;
  ushort_t* Vpx = Vcy + hb_sz;     ushort_t* Vpy = Vpx + hb_sz;
  ushort_t* xbfx = Vpy + hb_sz;    ushort_t* xbfy = xbfx + xbf_sz;
  ushort_t* Wtx  = xbfy + xbf_sz;  ushort_t* Wty  = Wtx + wt_sz;
  float* qwx = (float*)(Wty + wt_sz);
  float* kwx = qwx + win_sz;
  float* qwy = kwx + win_sz;
  float* kwy = qwy + win_sz;
  int* idxx = (int*)(kwy + win_sz);
  int* idxy = idxx + NB * P2 * 4;

  meanproj_kernel<<<dim3(NB, P2, 2), 256, 0, stream>>>(
      x, y, w_qkv_x, b_qkv_x, w_qkv_y, b_qkv_y, xbfx, xbfy, Wtx, Wty,
      qwx, kwx, qwy, kwy);
  route_kernel<<<dim3(2, NB), 256, 0, stream>>>(qwx, kwx, qwy, kwy, idxx, idxy);
  qkv_gemm_kernel<<<dim3(NB, P2, 2), 256, 0, stream>>>(
      xbfx, xbfy, Wtx, Wty, b_qkv_x, b_qkv_y,
      Qpx, Qpy, Kpx, Kpy, Vcx, Vcy, Vpx, Vpy);
  attn_kernel<<<dim3(NB, P2, 16), 256, 0, stream>>>(
      Qpx, Qpy, Kpx, Kpy, Vcx, Vcy, Vpx, Vpy, idxx, idxy,
      w_lepe_x, b_lepe_x, w_lepe_y, b_lepe_y, out);
}

// Round 7
// 199.150 us; speedup vs baseline: 1.2290x; 1.1095x over previous
//
#include <hip/hip_runtime.h>

#define HWD 56
#define NWIN 7
#define P2 49
#define CIN 128
#define COUT 384
#define NB 8
#define SCALE 0.08838834764831843f

typedef __attribute__((ext_vector_type(8))) short bf16x8;
typedef __attribute__((ext_vector_type(4))) float f32x4;
typedef __attribute__((ext_vector_type(8))) unsigned short u16x8;
typedef unsigned short ushort_t;

#if __has_builtin(__builtin_amdgcn_mfma_f32_16x16x16bf16_1k)
#define HAVE_MFMA16 1
typedef __attribute__((ext_vector_type(4))) short bf16x4;
#endif

__device__ inline unsigned short f2bf(float f) {
  unsigned int u = __float_as_uint(f);
  unsigned int r = (u + 0x7fffu + ((u >> 16) & 1u)) >> 16;
  return (unsigned short)r;
}
__device__ inline float bf2f(unsigned short b) {
  return __uint_as_float(((unsigned int)b) << 16);
}
// packed f32x2 -> bf16x2 (RNE); hw v_cvt_pk_bf16_f32 when available
__device__ inline unsigned int pk2bf(float a, float b) {
#if __has_builtin(__builtin_amdgcn_cvt_pk_bf16_f32)
  auto r = __builtin_amdgcn_cvt_pk_bf16_f32(a, b);
  return *(unsigned int*)&r;
#else
  return (unsigned int)f2bf(a) | ((unsigned int)f2bf(b) << 16);
#endif
}

// ---------------- W transpose -> bf16 Wt[cout][k] ----------------
// grid (3, 2), block 128
__global__ __launch_bounds__(128) void wt_kernel(
    const float* __restrict__ Wx, const float* __restrict__ Wy,
    ushort_t* __restrict__ Wtx, ushort_t* __restrict__ Wty)
{
  const int br = blockIdx.y;
  const float* W = br ? Wy : Wx;
  ushort_t* Wt = br ? Wty : Wtx;
  const int c = blockIdx.x * 128 + threadIdx.x;
  for (int k8 = 0; k8 < 128; k8 += 8) {
    u16x8 buf;
#pragma unroll
    for (int i = 0; i < 8; ++i) buf[i] = f2bf(W[(size_t)(k8 + i) * COUT + c]);
    *(u16x8*)&Wt[(size_t)c * 128 + k8] = buf;
  }
}

// ---------------- FUSED: x-window stage + bf16 GEMM + fp32 mean/routing-proj ----------------
// Qp/Kp: [win][head 8][pix 64][16ch] (q pre-scaled); Vc: [win][head][16ch][pix]; Vp like Qp.
// grid (8, 49, 2): x=n (XCD affinity), y=p, z=br; block 256 = 4 waves; wave wv: couts [96wv,96wv+96)
#define XS 136
__global__ __launch_bounds__(256) void fused_gemm_kernel(
    const float* __restrict__ xin, const float* __restrict__ yin,
    const float* __restrict__ Wx, const float* __restrict__ Wy,
    const ushort_t* __restrict__ Wtx, const ushort_t* __restrict__ Wty,
    const float* __restrict__ Bx, const float* __restrict__ By,
    ushort_t* __restrict__ Qpx, ushort_t* __restrict__ Qpy,
    ushort_t* __restrict__ Kpx, ushort_t* __restrict__ Kpy,
    ushort_t* __restrict__ Vcx, ushort_t* __restrict__ Vcy,
    ushort_t* __restrict__ Vpx, ushort_t* __restrict__ Vpy,
    float* __restrict__ qwx, float* __restrict__ kwx,
    float* __restrict__ qwy, float* __restrict__ kwy)
{
  const int n = blockIdx.x, p = blockIdx.y, br = blockIdx.z;
  const float* X  = br ? yin : xin;
  const float* W  = br ? Wy  : Wx;
  const ushort_t* Wt = br ? Wty : Wtx;
  const float* Bv = br ? By : Bx;
  ushort_t* Qp = br ? Qpy : Qpx;
  ushort_t* Kp = br ? Kpy : Kpx;
  ushort_t* Vc = br ? Vcy : Vcx;
  ushort_t* Vp = br ? Vpy : Vpx;
  float* qw = br ? qwy : qwx;
  float* kw = br ? kwy : kwx;

  __shared__ ushort_t a_s[64 * XS];   // [pix][k] bf16
  __shared__ float smf[8][132];       // per pixel-group channel sums
  __shared__ float mxs[128];          // window mean (fp32 exact)

  const int t = threadIdx.x;
  const int wr = p / NWIN, wc = p % NWIN;
  const int pr = t >> 5, ch4 = (t & 31) * 4;   // pixel-in-row, channel quad

  // stage x window (fp32 -> bf16) + accumulate fp32 channel sums
  float4 s4 = {0.f, 0.f, 0.f, 0.f};
#pragma unroll
  for (int i = 0; i < 8; ++i) {
    const float* Xrow = X + (((size_t)n * HWD + wr * 8 + i) * HWD + wc * 8) * CIN;
    float4 v = *(const float4*)&Xrow[pr * CIN + ch4];
    s4.x += v.x; s4.y += v.y; s4.z += v.z; s4.w += v.w;
    unsigned int lo = pk2bf(v.x, v.y), hi = pk2bf(v.z, v.w);
    uint2 st = {lo, hi};
    *(uint2*)&a_s[(i * 8 + pr) * XS + ch4] = st;
  }
  *(float4*)&smf[pr][ch4] = s4;
  __syncthreads();
  if (t < 128) {
    float s = 0.f;
#pragma unroll
    for (int g = 0; g < 8; ++g) s += smf[g][t];
    mxs[t] = s * (1.f / 64.f);
  }
  __syncthreads();

  // ---- GEMM: D = W x X^T, m=cout (reg rows), n=pix (lane col) ----
  const int wv = t >> 6, lane = t & 63, qd = lane >> 4, m16 = lane & 15;
  const ushort_t* Wb = Wt + (size_t)(wv * 96) * 128;

  f32x4 acc[4][6];
#pragma unroll
  for (int i = 0; i < 4; ++i)
#pragma unroll
    for (int j = 0; j < 6; ++j) acc[i][j] = (f32x4){0.f, 0.f, 0.f, 0.f};

#pragma unroll
  for (int ks = 0; ks < 4; ++ks) {
    bf16x8 af[4], bfw[6];
#pragma unroll
    for (int fi = 0; fi < 4; ++fi)
      af[fi] = *(const bf16x8*)&a_s[(fi * 16 + m16) * XS + ks * 32 + qd * 8];
#pragma unroll
    for (int fj = 0; fj < 6; ++fj)
      bfw[fj] = *(const bf16x8*)&Wb[(size_t)(fj * 16 + m16) * 128 + ks * 32 + qd * 8];
#pragma unroll
    for (int fi = 0; fi < 4; ++fi)
#pragma unroll
      for (int fj = 0; fj < 6; ++fj)
        acc[fi][fj] = __builtin_amdgcn_mfma_f32_16x16x32_bf16(bfw[fj], af[fi], acc[fi][fj], 0, 0, 0);
  }

  const size_t wb = (size_t)(n * P2 + p) * 8;
#pragma unroll
  for (int fj = 0; fj < 6; ++fj) {
    const int ch = wv * 96 + fj * 16 + qd * 4;
    float4 b4 = *(const float4*)&Bv[ch];
    const int isQ = ch < 128, isK = (ch >= 128) && (ch < 256);
    const float scl = isQ ? SCALE : 1.0f;
    const int lch = ch & 127, h = lch >> 4, chlo = lch & 15;
#pragma unroll
    for (int fi = 0; fi < 4; ++fi) {
      int pix = fi * 16 + m16;
      float v0 = (acc[fi][fj][0] + b4.x) * scl, v1 = (acc[fi][fj][1] + b4.y) * scl;
      float v2 = (acc[fi][fj][2] + b4.z) * scl, v3 = (acc[fi][fj][3] + b4.w) * scl;
      unsigned int lo = pk2bf(v0, v1), hi = pk2bf(v2, v3);
      uint2 st = {lo, hi};
      if (isQ) {
        *(uint2*)&Qp[((wb + h) * 64 + pix) * 16 + chlo] = st;
      } else if (isK) {
        *(uint2*)&Kp[((wb + h) * 64 + pix) * 16 + chlo] = st;
      } else {
        *(uint2*)&Vp[((wb + h) * 64 + pix) * 16 + chlo] = st;
        size_t cb = ((wb + h) * 16 + chlo) * 64 + pix;
        Vc[cb]       = (ushort_t)(lo & 0xffff);
        Vc[cb + 64]  = (ushort_t)(lo >> 16);
        Vc[cb + 128] = (ushort_t)(hi & 0xffff);
        Vc[cb + 192] = (ushort_t)(hi >> 16);
      }
    }
  }

  // ---- fp32 routing projection (exact path), after GEMM to unblock MFMA ----
  float accp = Bv[t];
#pragma unroll 8
  for (int k = 0; k < 128; ++k) accp = fmaf(mxs[k], W[(size_t)k * COUT + t], accp);
  if (t < 128) qw[(n * P2 + p) * 128 + t] = accp;
  else         kw[(n * P2 + p) * 128 + (t - 128)] = accp;
}

// ---------------- routing: top-4 per query row; grid (49, 8, 2), block 64 ----------------
__global__ __launch_bounds__(64) void route_kernel(
    const float* __restrict__ qwx, const float* __restrict__ kwx,
    const float* __restrict__ qwy, const float* __restrict__ kwy,
    int* __restrict__ idxx, int* __restrict__ idxy)
{
  const int r = blockIdx.x, n = blockIdx.y, br = blockIdx.z;
  const float* qw = br ? qwy : qwx;
  const float* kw = br ? kwy : kwx;
  int* idx = br ? idxy : idxx;

  const int lane = threadIdx.x;
  float2 q2 = *(const float2*)&qw[((size_t)n * P2 + r) * 128 + lane * 2];

  float v = -1e30f;
  for (int j = 0; j < P2; ++j) {
    float2 k2 = *(const float2*)&kw[((size_t)n * P2 + j) * 128 + lane * 2];
    float d = fmaf(q2.x, k2.x, q2.y * k2.y);
#pragma unroll
    for (int msk = 1; msk < 64; msk <<= 1) d += __shfl_xor(d, msk);
    if (lane == j) v = d;   // positive scale is monotone: ordering identical
  }

  int out4[4];
#pragma unroll
  for (int sel = 0; sel < 4; ++sel) {
    float m = v;
#pragma unroll
    for (int msk = 1; msk < 64; msk <<= 1) m = fmaxf(m, __shfl_xor(m, msk));
    unsigned long long b = __ballot(v == m);
    int bi = __ffsll(b) - 1;   // lowest index on ties (jax top_k)
    out4[sel] = bi;
    if (lane == bi) v = -1e30f;
  }
  if (lane == 0) {
    int4 o = {out4[0], out4[1], out4[2], out4[3]};
    *(int4*)&idx[((size_t)n * P2 + r) * 4] = o;
  }
}

// ---------------- fused attention + LEPE; MFMA operands direct-global, P via per-wave LDS ----------------
// grid (8, 49, 16): x=n, y=p, z=head*2+dir; block 256 = 4 waves (q-row tiles)
#define PBS 264   // per-row ushort stride in pb
__global__ __launch_bounds__(256) void attn_kernel(
    const ushort_t* __restrict__ Qpx, const ushort_t* __restrict__ Qpy,
    const ushort_t* __restrict__ Kpx, const ushort_t* __restrict__ Kpy,
    const ushort_t* __restrict__ Vcx, const ushort_t* __restrict__ Vcy,
    const ushort_t* __restrict__ Vpx, const ushort_t* __restrict__ Vpy,
    const int* __restrict__ idxx, const int* __restrict__ idxy,
    const float* __restrict__ wlx, const float* __restrict__ blx,
    const float* __restrict__ wly, const float* __restrict__ bly,
    float* __restrict__ dout)
{
  const int n = blockIdx.x, p = blockIdx.y, z = blockIdx.z;
  const int h = z >> 1, dir = z & 1;
  const ushort_t* Qp = dir ? Qpy : Qpx;
  const ushort_t* Kp = dir ? Kpy : Kpx;
  const ushort_t* Vc = dir ? Vcx : Vcy;   // cross-branch V
  const ushort_t* Vp = dir ? Vpx : Vpy;
  const int* idxK = dir ? idxy : idxx;
  const int* idxV = dir ? idxx : idxy;
  const float* wl = dir ? wlx : wly;      // dir0 writes out_y -> lepe_y
  const float* bl = dir ? blx : bly;
  const size_t OUTHALF = (size_t)NB * HWD * HWD * CIN;
  float* outp = dout + (dir ? 0 : OUTHALF);

  __shared__ float halo[100 * 20];          // [10x10 pix][16ch fp32]
  __shared__ float wls[160];                // taps 0..8 x16ch + bias x16ch
  __shared__ ushort_t pb[4 * 16 * PBS];     // per-wave P scratch [qrow][key]

  const int t = threadIdx.x;
  const int wv = t >> 6;
  const int wr = p / NWIN, wc = p % NWIN;

  const int4 kidx = *(const int4*)&idxK[((size_t)n * P2 + p) * 4];
  const int4 vidx = *(const int4*)&idxV[((size_t)n * P2 + p) * 4];
  const int kw4[4] = {kidx.x, kidx.y, kidx.z, kidx.w};
  const int vw4[4] = {vidx.x, vidx.y, vidx.z, vidx.w};

  // LEPE halo: 10x10 x 16ch fp32 (zero outside)
  if (t < 200) {
    int hp = t >> 1, hf = t & 1;
    int A = wr * 8 - 1 + (int)((unsigned)hp / 10u);
    int B = wc * 8 - 1 + (int)((unsigned)hp % 10u);
    f32x4 f0 = {0.f, 0.f, 0.f, 0.f}, f1 = {0.f, 0.f, 0.f, 0.f};
    if ((unsigned)A < (unsigned)HWD && (unsigned)B < (unsigned)HWD) {
      int gw = (A >> 3) * NWIN + (B >> 3);
      int pix = (A & 7) * 8 + (B & 7);
      u16x8 vv = *(const u16x8*)&Vp[(((size_t)(n * P2 + gw) * 8 + h) * 64 + pix) * 16 + hf * 8];
      f0[0] = bf2f(vv[0]); f0[1] = bf2f(vv[1]); f0[2] = bf2f(vv[2]); f0[3] = bf2f(vv[3]);
      f1[0] = bf2f(vv[4]); f1[1] = bf2f(vv[5]); f1[2] = bf2f(vv[6]); f1[3] = bf2f(vv[7]);
    }
    *(f32x4*)&halo[hp * 20 + hf * 8] = f0;
    *(f32x4*)&halo[hp * 20 + hf * 8 + 4] = f1;
  }
  if (t < 160) {
    int row = t >> 4, c = t & 15;
    wls[t] = (row < 9) ? wl[(h * 16 + c) * 9 + row] : bl[h * 16 + c];
  }

  const int lane = t & 63, qd = lane >> 4, m16 = lane & 15;
  const f32x4 zf = {0.f, 0.f, 0.f, 0.f};
  const ushort_t* Qw = Qp + ((size_t)(n * P2 + p) * 8 + h) * 1024;

  // Phase 1: S^T = K x Q^T (C: col=qrow m16, reg row=key qd*4+rr)
  f32x4 s[8][2];
#if HAVE_MFMA16
  bf16x4 qf = *(const bf16x4*)&Qw[(wv * 16 + m16) * 16 + qd * 4];
#pragma unroll
  for (int c = 0; c < 8; ++c) {
    const ushort_t* Kw = Kp + ((size_t)(n * P2 + kw4[c >> 1]) * 8 + h) * 1024;
    int lk = (c & 1) * 32;
    bf16x4 kf0 = *(const bf16x4*)&Kw[(lk + m16) * 16 + qd * 4];
    bf16x4 kf1 = *(const bf16x4*)&Kw[(lk + 16 + m16) * 16 + qd * 4];
    s[c][0] = __builtin_amdgcn_mfma_f32_16x16x16bf16_1k(kf0, qf, zf, 0, 0, 0);
    s[c][1] = __builtin_amdgcn_mfma_f32_16x16x16bf16_1k(kf1, qf, zf, 0, 0, 0);
  }
#else
  bf16x8 qf = (bf16x8)(short)0;
  if (qd < 2) qf = *(const bf16x8*)&Qw[(wv * 16 + m16) * 16 + qd * 8];
#pragma unroll
  for (int c = 0; c < 8; ++c) {
    const ushort_t* Kw = Kp + ((size_t)(n * P2 + kw4[c >> 1]) * 8 + h) * 1024;
    int lk = (c & 1) * 32;
    bf16x8 kf0 = (bf16x8)(short)0, kf1 = (bf16x8)(short)0;
    if (qd < 2) {
      kf0 = *(const bf16x8*)&Kw[(lk + m16) * 16 + qd * 8];
      kf1 = *(const bf16x8*)&Kw[(lk + 16 + m16) * 16 + qd * 8];
    }
    s[c][0] = __builtin_amdgcn_mfma_f32_16x16x32_bf16(kf0, qf, zf, 0, 0, 0);
    s[c][1] = __builtin_amdgcn_mfma_f32_16x16x32_bf16(kf1, qf, zf, 0, 0, 0);
  }
#endif

  // Phase 2: single-pass softmax over 256 keys (lane-local per q-row)
  float m = -1e30f;
#pragma unroll
  for (int c = 0; c < 8; ++c)
#pragma unroll
    for (int hh = 0; hh < 2; ++hh)
#pragma unroll
      for (int rr = 0; rr < 4; ++rr) m = fmaxf(m, s[c][hh][rr]);
  m = fmaxf(m, __shfl_xor(m, 16));
  m = fmaxf(m, __shfl_xor(m, 32));
  float l = 0.f;
#pragma unroll
  for (int c = 0; c < 8; ++c)
#pragma unroll
    for (int hh = 0; hh < 2; ++hh)
#pragma unroll
      for (int rr = 0; rr < 4; ++rr) {
        float e = __expf(s[c][hh][rr] - m);
        s[c][hh][rr] = e;
        l += e;
      }
  l += __shfl_xor(l, 16);
  l += __shfl_xor(l, 32);
  const float inv = 1.f / l;

  // Phase 2.5: P -> per-wave LDS (wave-local, no barrier; lgkmcnt handles write->read)
  ushort_t* pbw = pb + wv * 16 * PBS + m16 * PBS;
#pragma unroll
  for (int c = 0; c < 8; ++c) {
    uint2 lo = {pk2bf(s[c][0][0], s[c][0][1]), pk2bf(s[c][0][2], s[c][0][3])};
    uint2 hi = {pk2bf(s[c][1][0], s[c][1][1]), pk2bf(s[c][1][2], s[c][1][3])};
    *(uint2*)&pbw[c * 32 + qd * 4] = lo;
    *(uint2*)&pbw[c * 32 + qd * 4 + 16] = hi;
  }

  // Phase 3: O^T = V^T x P^T; P B-frags from own wave's LDS rows
  f32x4 oacc = {0.f, 0.f, 0.f, 0.f};
#pragma unroll
  for (int c = 0; c < 8; ++c) {
    u16x8 pfu = *(const u16x8*)&pbw[c * 32 + qd * 8];
    const ushort_t* Vw = Vc + ((size_t)(n * P2 + vw4[c >> 1]) * 8 + h) * 1024;
    bf16x8 vtf = *(const bf16x8*)&Vw[m16 * 64 + (c & 1) * 32 + qd * 8];
    oacc = __builtin_amdgcn_mfma_f32_16x16x32_bf16(vtf, *(bf16x8*)&pfu, oacc, 0, 0, 0);
  }

  __syncthreads();  // halo + wls visibility

  const int pix = wv * 16 + m16;
  const int pa = pix >> 3, pb2 = pix & 7;

  f32x4 lep = *(const f32x4*)&wls[144 + qd * 4];
#pragma unroll
  for (int di = 0; di < 3; ++di)
#pragma unroll
    for (int dj = 0; dj < 3; ++dj) {
      f32x4 hv = *(const f32x4*)&halo[((pa + di) * 10 + pb2 + dj) * 20 + qd * 4];
      f32x4 wt4 = *(const f32x4*)&wls[(di * 3 + dj) * 16 + qd * 4];
#pragma unroll
      for (int rr = 0; rr < 4; ++rr) lep[rr] = fmaf(hv[rr], wt4[rr], lep[rr]);
    }

  const int ga = wr * 8 + pa, gb = wc * 8 + pb2;
  float4 o = {oacc[0] * inv + lep[0], oacc[1] * inv + lep[1],
              oacc[2] * inv + lep[2], oacc[3] * inv + lep[3]};
  *(float4*)&outp[(((size_t)n * HWD + ga) * HWD + gb) * CIN + h * 16 + qd * 4] = o;
}

extern "C" void kernel_launch(void* const* d_in, const int* in_sizes, int n_in,
                              void* d_out, int out_size, void* d_ws, size_t ws_size,
                              hipStream_t stream) {
  const float* x        = (const float*)d_in[0];
  const float* y        = (const float*)d_in[1];
  const float* w_qkv_x  = (const float*)d_in[2];
  const float* b_qkv_x  = (const float*)d_in[3];
  const float* w_qkv_y  = (const float*)d_in[4];
  const float* b_qkv_y  = (const float*)d_in[5];
  const float* w_lepe_x = (const float*)d_in[6];
  const float* b_lepe_x = (const float*)d_in[7];
  const float* w_lepe_y = (const float*)d_in[8];
  const float* b_lepe_y = (const float*)d_in[9];
  float* out = (float*)d_out;

  const size_t hb_sz  = (size_t)NB * P2 * 8 * 64 * 16;  // head-blocked tensor, bf16 elems
  const size_t wt_sz  = (size_t)COUT * CIN;
  const size_t win_sz = (size_t)NB * P2 * 128;

  ushort_t* base = (ushort_t*)d_ws;
  ushort_t* Qpx = base;            ushort_t* Qpy = Qpx + hb_sz;
  ushort_t* Kpx = Qpy + hb_sz;     ushort_t* Kpy = Kpx + hb_sz;
  ushort_t* Vcx = Kpy + hb_sz;     ushort_t* Vcy = Vcx + hb_sz;
  ushort_t* Vpx = Vcy + hb_sz;     ushort_t* Vpy = Vpx + hb_sz;
  ushort_t* Wtx = Vpy + hb_sz;     ushort_t* Wty = Wtx + wt_sz;
  float* qwx = (float*)(Wty + wt_sz);
  float* kwx = qwx + win_sz;
  float* qwy = kwx + win_sz;
  float* kwy = qwy + win_sz;
  int* idxx = (int*)(kwy + win_sz);
  int* idxy = idxx + NB * P2 * 4;

  wt_kernel<<<dim3(3, 2), 128, 0, stream>>>(w_qkv_x, w_qkv_y, Wtx, Wty);
  fused_gemm_kernel<<<dim3(NB, P2, 2), 256, 0, stream>>>(
      x, y, w_qkv_x, w_qkv_y, Wtx, Wty, b_qkv_x, b_qkv_y,
      Qpx, Qpy, Kpx, Kpy, Vcx, Vcy, Vpx, Vpy, qwx, kwx, qwy, kwy);
  route_kernel<<<dim3(P2, NB, 2), 64, 0, stream>>>(qwx, kwx, qwy, kwy, idxx, idxy);
  attn_kernel<<<dim3(NB, P2, 16), 256, 0, stream>>>(
      Qpx, Qpy, Kpx, Kpy, Vcx, Vcy, Vpx, Vpy, idxx, idxy,
      w_lepe_x, b_lepe_x, w_lepe_y, b_lepe_y, out);
}